// Round 3
// baseline (28.575 us; speedup 1.0000x reference)
//
#include <hip/hip_runtime.h>
#include <stdint.h>

#define NF   2344
#define ACCW 8
#define NA   38
#define TPB  256
#define EPT  2   // elements per thread

__device__ __forceinline__ unsigned short f32_to_bf16(float f) {
    unsigned u = __float_as_uint(f);
    u += 0x7FFFu + ((u >> 16) & 1u);   // round-to-nearest-even
    return (unsigned short)(u >> 16);
}
__device__ __forceinline__ float bf16_lo(unsigned u) { return __uint_as_float(u << 16); }
__device__ __forceinline__ float bf16_hi(unsigned u) { return __uint_as_float(u & 0xFFFF0000u); }

__global__ __launch_bounds__(TPB, 2) void nnue_fwd(
    const int* __restrict__ bfeat, const int* __restrict__ wfeat,
    const int* __restrict__ stm,
    const float* __restrict__ w1, const float* __restrict__ b1,
    const float* __restrict__ w2, const float* __restrict__ b2,
    float* __restrict__ out, int nbatch)
{
    __shared__ unsigned short tbl[NF * ACCW];   // bf16 table, 16B per row

    // ---- stage fp32 table -> bf16 LDS (coalesced float4 reads) ----
    for (int j = threadIdx.x; j < (NF * ACCW) / 4; j += TPB) {
        float4 v = reinterpret_cast<const float4*>(w1)[j];
        unsigned lo = (unsigned)f32_to_bf16(v.x) | ((unsigned)f32_to_bf16(v.y) << 16);
        unsigned hi = (unsigned)f32_to_bf16(v.z) | ((unsigned)f32_to_bf16(v.w) << 16);
        reinterpret_cast<uint2*>(tbl)[j] = make_uint2(lo, hi);
    }
    __syncthreads();

    const int tid = blockIdx.x * TPB + threadIdx.x;
    const int e0  = tid * EPT;
    if (e0 >= nbatch) return;

    // uniform small params (scalar-promoted loads)
    float biasr[8];
#pragma unroll
    for (int k = 0; k < 8; ++k) biasr[k] = b1[k];
    float w2lo[8], w2hi[8];
#pragma unroll
    for (int k = 0; k < 8; ++k) { w2lo[k] = w2[k]; w2hi[k] = w2[8 + k]; }
    const float c2 = b2[0];

#define GATHER(acc, idx) { \
        uint4 r = *reinterpret_cast<const uint4*>( \
            reinterpret_cast<const char*>(tbl) + ((unsigned)(idx) << 4)); \
        acc[0] += bf16_lo(r.x); acc[1] += bf16_hi(r.x); \
        acc[2] += bf16_lo(r.y); acc[3] += bf16_hi(r.y); \
        acc[4] += bf16_lo(r.z); acc[5] += bf16_hi(r.z); \
        acc[6] += bf16_lo(r.w); acc[7] += bf16_hi(r.w); }

    float aB0[8], aB1[8], aW0[8], aW1[8];
#pragma unroll
    for (int k = 0; k < 8; ++k) { aB0[k] = biasr[k]; aB1[k] = biasr[k]; }

    // ---- black: 19 aligned int4 loads cover both elements' 38 indices ----
    {
        int4 q[19];
        const int4* p = reinterpret_cast<const int4*>(bfeat + (long)e0 * NA);
#pragma unroll
        for (int j = 0; j < 19; ++j) q[j] = p[j];
        const int* qi = reinterpret_cast<const int*>(q);
#pragma unroll
        for (int i = 0; i < NA; ++i) {
            GATHER(aB0, qi[i]);
            GATHER(aB1, qi[NA + i]);
        }
    }

#pragma unroll
    for (int k = 0; k < 8; ++k) { aW0[k] = biasr[k]; aW1[k] = biasr[k]; }

    // ---- white ----
    {
        int4 q[19];
        const int4* p = reinterpret_cast<const int4*>(wfeat + (long)e0 * NA);
#pragma unroll
        for (int j = 0; j < 19; ++j) q[j] = p[j];
        const int* qi = reinterpret_cast<const int*>(q);
#pragma unroll
        for (int i = 0; i < NA; ++i) {
            GATHER(aW0, qi[i]);
            GATHER(aW1, qi[NA + i]);
        }
    }
#undef GATHER

    // ---- finale: clip, stm-ordered dot (branchless: compute both halves) ----
    const int2 sp = *reinterpret_cast<const int2*>(stm + e0);

    float res[EPT];
    {
        float dbl = 0.f, dbh = 0.f, dwl = 0.f, dwh = 0.f;
#pragma unroll
        for (int c = 0; c < 8; ++c) {
            float bv = fminf(fmaxf(aB0[c], 0.f), 1.f);
            float wv = fminf(fmaxf(aW0[c], 0.f), 1.f);
            dbl += bv * w2lo[c]; dbh += bv * w2hi[c];
            dwl += wv * w2lo[c]; dwh += wv * w2hi[c];
        }
        res[0] = c2 + (sp.x == 0 ? (dbl + dwh) : (dbh + dwl));
    }
    {
        float dbl = 0.f, dbh = 0.f, dwl = 0.f, dwh = 0.f;
#pragma unroll
        for (int c = 0; c < 8; ++c) {
            float bv = fminf(fmaxf(aB1[c], 0.f), 1.f);
            float wv = fminf(fmaxf(aW1[c], 0.f), 1.f);
            dbl += bv * w2lo[c]; dbh += bv * w2hi[c];
            dwl += wv * w2lo[c]; dwh += wv * w2hi[c];
        }
        res[1] = c2 + (sp.y == 0 ? (dbl + dwh) : (dbh + dwl));
    }

    *reinterpret_cast<float2*>(out + e0) = make_float2(res[0], res[1]);
}

extern "C" void kernel_launch(void* const* d_in, const int* in_sizes, int n_in,
                              void* d_out, int out_size, void* d_ws, size_t ws_size,
                              hipStream_t stream) {
    const int*   bfeat = (const int*)  d_in[0];
    const int*   wfeat = (const int*)  d_in[1];
    const int*   stm   = (const int*)  d_in[2];
    const float* w1    = (const float*)d_in[3];
    const float* b1    = (const float*)d_in[4];
    const float* w2    = (const float*)d_in[5];
    const float* b2    = (const float*)d_in[6];
    float* out = (float*)d_out;

    const int nbatch = in_sizes[2];
    const int grid = (nbatch + TPB * EPT - 1) / (TPB * EPT);
    nnue_fwd<<<grid, TPB, 0, stream>>>(bfeat, wfeat, stm, w1, b1, w2, b2, out, nbatch);
}

// Round 4
// 25.011 us; speedup vs baseline: 1.1425x; 1.1425x over previous
//
#include <hip/hip_runtime.h>
#include <stdint.h>

#define NF   2344
#define ACCW 8
#define NA   38
#define TPB  1024   // 16 waves/block; 2 blocks/CU -> 32 waves/CU (needs VGPR<=64)

__device__ __forceinline__ unsigned short f32_to_bf16(float f) {
    unsigned u = __float_as_uint(f);
    u += 0x7FFFu + ((u >> 16) & 1u);   // round-to-nearest-even
    return (unsigned short)(u >> 16);
}
__device__ __forceinline__ float bf16_lo(unsigned u) { return __uint_as_float(u << 16); }
__device__ __forceinline__ float bf16_hi(unsigned u) { return __uint_as_float(u & 0xFFFF0000u); }

// One thread = one (element, color). Even lane: black, odd lane: white.
// Pair combines via shfl_xor(1); even lane writes the output.
__global__ __launch_bounds__(TPB, 8) void nnue_fwd(
    const int* __restrict__ bfeat, const int* __restrict__ wfeat,
    const int* __restrict__ stm,
    const float* __restrict__ w1, const float* __restrict__ b1,
    const float* __restrict__ w2, const float* __restrict__ b2,
    float* __restrict__ out, int nbatch)
{
    __shared__ unsigned short tbl[NF * ACCW];   // bf16 table, 16B per row (37.9 KB)

    // ---- stage fp32 table -> bf16 LDS (coalesced float4 reads, ~4.6 iters) ----
    for (int j = threadIdx.x; j < (NF * ACCW) / 4; j += TPB) {
        float4 v = reinterpret_cast<const float4*>(w1)[j];
        unsigned lo = (unsigned)f32_to_bf16(v.x) | ((unsigned)f32_to_bf16(v.y) << 16);
        unsigned hi = (unsigned)f32_to_bf16(v.z) | ((unsigned)f32_to_bf16(v.w) << 16);
        reinterpret_cast<uint2*>(tbl)[j] = make_uint2(lo, hi);
    }
    __syncthreads();

    const int t = blockIdx.x * TPB + threadIdx.x;
    const int e = t >> 1;            // batch element
    const int c = t & 1;             // 0 = black, 1 = white
    if (e >= nbatch) return;

    const int* __restrict__ feat = c ? wfeat : bfeat;

    // accumulator starts at bias (b1/w2/b2 are uniform -> scalar loads/SGPRs)
    float acc[8];
#pragma unroll
    for (int k = 0; k < 8; ++k) acc[k] = b1[k];

    // ---- 19 aligned int2 loads cover this (element,color)'s 38 indices ----
    int2 q[19];
    {
        const int2* p = reinterpret_cast<const int2*>(feat + (long)e * NA);
#pragma unroll
        for (int j = 0; j < 19; ++j) q[j] = p[j];
    }
    const int* qi = reinterpret_cast<const int*>(q);

    // ---- 38 LDS row gathers (ds_read_b128), fp32 accumulate ----
#pragma unroll
    for (int i = 0; i < NA; ++i) {
        uint4 r = *reinterpret_cast<const uint4*>(
            reinterpret_cast<const char*>(tbl) + ((unsigned)qi[i] << 4));
        acc[0] += bf16_lo(r.x); acc[1] += bf16_hi(r.x);
        acc[2] += bf16_lo(r.y); acc[3] += bf16_hi(r.y);
        acc[4] += bf16_lo(r.z); acc[5] += bf16_hi(r.z);
        acc[6] += bf16_lo(r.w); acc[7] += bf16_hi(r.w);
    }

    // ---- clip + both dot halves ----
    float dlo = 0.f, dhi = 0.f;
#pragma unroll
    for (int k = 0; k < 8; ++k) {
        float v = fminf(fmaxf(acc[k], 0.f), 1.f);
        dlo += v * w2[k];
        dhi += v * w2[8 + k];
    }

    // stm ordering: bw (s==0) -> black uses w2[0:8], white uses w2[8:16]; wb swaps.
    const int s = stm[e];
    const float mine  = (((s == 0)) == (c == 0)) ? dlo : dhi;
    const float other = __shfl_xor(mine, 1);
    if (c == 0) out[e] = mine + other + b2[0];
}

extern "C" void kernel_launch(void* const* d_in, const int* in_sizes, int n_in,
                              void* d_out, int out_size, void* d_ws, size_t ws_size,
                              hipStream_t stream) {
    const int*   bfeat = (const int*)  d_in[0];
    const int*   wfeat = (const int*)  d_in[1];
    const int*   stm   = (const int*)  d_in[2];
    const float* w1    = (const float*)d_in[3];
    const float* b1    = (const float*)d_in[4];
    const float* w2    = (const float*)d_in[5];
    const float* b2    = (const float*)d_in[6];
    float* out = (float*)d_out;

    const int nbatch  = in_sizes[2];
    const long nthread = (long)nbatch * 2;           // 2 threads per element
    const int grid = (int)((nthread + TPB - 1) / TPB);
    nnue_fwd<<<grid, TPB, 0, stream>>>(bfeat, wfeat, stm, w1, b1, w2, b2, out, nbatch);
}